// Round 6
// baseline (293.412 us; speedup 1.0000x reference)
//
#include <hip/hip_runtime.h>
#include <hip/hip_bf16.h>
#include <stdint.h>

// HS-MSA: QKV proj (bf16 MFMA GEMM, single-fetch A-resident) -> fused
// swapped-operand MFMA flash attention (both branches, one dispatch,
// fixed-max softmax) -> out proj + bias.
//
// ws layout (bytes):
//   [0,        393216)   WqkvT bf16 [768][256]
//   [393216,   524288)   WoT   bf16 [256][256]
//   [524288,  101187584) QKV   bf16 [65536][768] windowed rows; Q:0-255 K:256-511 V:512-767
//   [101187584, 134742016) attnO bf16 [65536][256]

typedef float f32x4 __attribute__((ext_vector_type(4)));
typedef __bf16 bf16_t;
typedef __bf16 bf16x8 __attribute__((ext_vector_type(8)));
typedef __bf16 bf16x4 __attribute__((ext_vector_type(4)));
typedef __bf16 bf16x2 __attribute__((ext_vector_type(2)));

#define SCALE_F 0.17677669529663687f
#define FIXMAX 8.0f

__device__ __forceinline__ int token_of_row(int gr) {
  int b = gr >> 14, n = (gr >> 6) & 255, m = gr & 63;
  int h = ((n >> 4) << 3) + (m >> 3);
  int w = ((n & 15) << 3) + (m & 7);
  return ((b << 7) + h) * 128 + w;
}

// bank swizzle for V^T tiles: XOR bits 4-6 with bits 7-9 (region 128-aligned)
__device__ __forceinline__ int swz(int byte) {
  return byte ^ (((byte >> 7) & 7) << 4);
}

// ---------------- prep: weight transpose + bf16 ----------------
__global__ __launch_bounds__(256) void prep_k(
    const float* __restrict__ Wq, const float* __restrict__ Wkv,
    const float* __restrict__ Wo, bf16_t* __restrict__ WqkvT,
    bf16_t* __restrict__ WoT) {
  int tid = blockIdx.x * 256 + threadIdx.x;
  if (tid < 196608) {
    int k = tid / 768, c = tid % 768;
    float v = (c < 256) ? Wq[k * 256 + c] : Wkv[k * 512 + (c - 256)];
    WqkvT[c * 256 + k] = (bf16_t)v;
  } else if (tid < 262144) {
    int t = tid - 196608;
    int k = t >> 8, c = t & 255;
    WoT[c * 256 + k] = (bf16_t)Wo[k * 256 + c];
  }
}

// ---------------- GEMM1: QKV(bf16) = x @ [Wq|Wk|Wv], A-resident ----------------
__global__ __launch_bounds__(256, 2) void gemm_qkv_k(
    const float* __restrict__ x, const bf16_t* __restrict__ Wt,
    bf16_t* __restrict__ QKV) {
  __shared__ char lds[81920];
  char* Bs = lds + 65536;
  const int tid = threadIdx.x;
  const int row0 = blockIdx.x * 128;
  const int lane = tid & 63, wv = tid >> 6;
  const int wm = (wv >> 1) * 64, wn = (wv & 1) * 64;
  const int g = lane >> 4, c = lane & 15;

#pragma unroll
  for (int it = 0; it < 16; ++it) {
    int u = it * 256 + tid;
    int row = u >> 5;
    int kf4 = (u & 31) * 8;
    const float* src = x + (size_t)token_of_row(row0 + row) * 256 + kf4;
    f32x4 a0 = *(const f32x4*)src;
    f32x4 a1 = *(const f32x4*)(src + 4);
    bf16x8 o;
    o[0]=(bf16_t)a0[0]; o[1]=(bf16_t)a0[1]; o[2]=(bf16_t)a0[2]; o[3]=(bf16_t)a0[3];
    o[4]=(bf16_t)a1[0]; o[5]=(bf16_t)a1[1]; o[6]=(bf16_t)a1[2]; o[7]=(bf16_t)a1[3];
    int bo = (u & 31) * 16;
    *(bf16x8*)(lds + row * 512 + (bo ^ ((row & 7) << 4))) = o;
  }
  __syncthreads();

  for (int nc = 0; nc < 6; ++nc) {
    f32x4 acc[4][4];
#pragma unroll
    for (int m = 0; m < 4; ++m)
#pragma unroll
      for (int n = 0; n < 4; ++n) acc[m][n] = 0.f;

    for (int kc = 0; kc < 4; ++kc) {
#pragma unroll
      for (int j = 0; j < 4; ++j) {
        int unit = tid * 4 + j;
        int col = unit >> 3, kp = unit & 7;
        int4 w = *(const int4*)((const char*)Wt +
            (size_t)(nc * 128 + col) * 512 + kc * 128 + kp * 16);
        *(int4*)(Bs + col * 128 + ((kp * 16) ^ ((col & 7) << 4))) = w;
      }
      __syncthreads();

#pragma unroll
      for (int kf = 0; kf < 2; ++kf) {
        bf16x8 aF[4], bF[4];
        int kbyteA = kc * 128 + kf * 64 + g * 16;
        int kbyteB = kf * 64 + g * 16;
#pragma unroll
        for (int m = 0; m < 4; ++m) {
          int row = wm + m * 16 + c;
          aF[m] = *(const bf16x8*)(lds + row * 512 + (kbyteA ^ ((row & 7) << 4)));
        }
#pragma unroll
        for (int n = 0; n < 4; ++n) {
          int col = wn + n * 16 + c;
          bF[n] = *(const bf16x8*)(Bs + col * 128 + (kbyteB ^ ((col & 7) << 4)));
        }
#pragma unroll
        for (int m = 0; m < 4; ++m)
#pragma unroll
          for (int n = 0; n < 4; ++n)
            acc[m][n] = __builtin_amdgcn_mfma_f32_16x16x32_bf16(aF[m], bF[n], acc[m][n], 0, 0, 0);
      }
      __syncthreads();
    }

#pragma unroll
    for (int m = 0; m < 4; ++m) {
#pragma unroll
      for (int r = 0; r < 4; ++r) {
        int grow = row0 + wm + m * 16 + (g << 2) + r;
        bf16_t* dst = QKV + (size_t)grow * 768 + nc * 128 + wn + c;
#pragma unroll
        for (int n = 0; n < 4; ++n) dst[n * 16] = (bf16_t)acc[m][n][r];
      }
    }
  }
}

// ---------------- fused attention: even bid = branch1, odd bid = branch2 ----------------
// branch1 LDS: K [4h][64key][80B] @0 ; Vt [4h][32d][144B] @20480 ; P/wave 2KB @38912
// branch2 LDS: K [256key][80B] @0 ;   Vt [32d][528B]     @20480 ; P/wave 2KB @37376
__global__ __launch_bounds__(256, 3) void attn_k(
    const bf16_t* __restrict__ QKV, const float* __restrict__ pos1,
    const float* __restrict__ pos2, bf16_t* __restrict__ O) {
  __shared__ char lds[47104];
  const int bid = blockIdx.x;
  const int idx = bid >> 1;
  const int tid = threadIdx.x;
  const int lane = tid & 63;
  const int g = lane >> 4, c = lane & 15;

  if ((bid & 1) == 0) {
    // ---------- branch 1: block=(b,n), wave=head ----------
    const int n = idx & 255, b = idx >> 8;
    const int h = tid >> 6;
    char* Pw = lds + 38912 + h * 2048;
    const size_t rowbase = (size_t)(b * 256 + n) * 64;
    const char* base = (const char*)QKV + rowbase * 1536;

#pragma unroll
    for (int it = 0; it < 4; ++it) {
      int i2 = it * 256 + tid;
      int hh = i2 >> 8, key = (i2 >> 2) & 63, ch4 = i2 & 3;
      int4 kk = *(const int4*)(base + (size_t)key * 1536 + 512 + 64 * hh + ch4 * 16);
      *(int4*)(lds + (hh * 64 + key) * 80 + ch4 * 16) = kk;
    }
#pragma unroll
    for (int it = 0; it < 4; ++it) {
      int i2 = it * 256 + tid;
      int hh = i2 >> 8, mm = (i2 >> 2) & 63, dq = i2 & 3;
      bf16x8 vv = *(const bf16x8*)(base + (size_t)mm * 1536 + 1024 + 64 * hh + dq * 16);
#pragma unroll
      for (int j = 0; j < 8; ++j)
        *(bf16_t*)(lds + 20480 + swz(hh * 4608 + (dq * 8 + j) * 144 + mm * 2)) = vv[j];
    }

    bf16x8 qa[4];
#pragma unroll
    for (int qf = 0; qf < 4; ++qf)
      qa[qf] = *(const bf16x8*)(base + (size_t)(qf * 16 + c) * 1536 + 64 * h + 16 * g);
    __syncthreads();

    bf16x8 kfr[4];
#pragma unroll
    for (int kf = 0; kf < 4; ++kf)
      kfr[kf] = *(const bf16x8*)(lds + (h * 64 + kf * 16 + c) * 80 + 16 * g);
    bf16x8 vfr[2][2];
#pragma unroll
    for (int kb = 0; kb < 2; ++kb)
#pragma unroll
      for (int dt = 0; dt < 2; ++dt)
        vfr[kb][dt] = *(const bf16x8*)(lds + 20480 +
            swz(h * 4608 + (dt * 16 + c) * 144 + kb * 64 + g * 16));

    f32x4 Ov[2][4];
#pragma unroll
    for (int dt = 0; dt < 2; ++dt)
#pragma unroll
      for (int qf = 0; qf < 4; ++qf) Ov[dt][qf] = 0.f;

#pragma unroll
    for (int qf = 0; qf < 4; ++qf) {
      const float* pp = pos1 + ((h * 64 + qf * 16 + c) * 64 + 4 * g);
      f32x4 pv[4];
#pragma unroll
      for (int kf = 0; kf < 4; ++kf) pv[kf] = *(const f32x4*)(pp + kf * 16);
      f32x4 S[4];
#pragma unroll
      for (int kf = 0; kf < 4; ++kf) {
        S[kf] = 0.f;
        S[kf] = __builtin_amdgcn_mfma_f32_16x16x32_bf16(kfr[kf], qa[qf], S[kf], 0, 0, 0);
      }
#pragma unroll
      for (int kf = 0; kf < 4; ++kf) S[kf] = S[kf] * SCALE_F + pv[kf];
      // fixed-max softmax (shift-invariant; |S| << FIXMAX+80 so no overflow)
      float ls = 0.f;
#pragma unroll
      for (int kf = 0; kf < 4; ++kf)
#pragma unroll
        for (int r = 0; r < 4; ++r) {
          S[kf][r] = __expf(S[kf][r] - FIXMAX);
          ls += S[kf][r];
        }
      ls += __shfl_xor(ls, 16);
      ls += __shfl_xor(ls, 32);
      float inv = 1.0f / ls;
#pragma unroll
      for (int kf = 0; kf < 4; ++kf)
#pragma unroll
        for (int p = 0; p < 2; ++p) {
          bf16x2 w;
          w[0] = (bf16_t)(S[kf][2 * p] * inv);
          w[1] = (bf16_t)(S[kf][2 * p + 1] * inv);
          int byteo = c * 128 + kf * 32 + g * 8 + p * 4;
          *(bf16x2*)(Pw + (byteo ^ ((c & 7) << 4))) = w;
        }
      bf16x8 pb0 = *(const bf16x8*)(Pw + ((c * 128 + g * 16) ^ ((c & 7) << 4)));
      bf16x8 pb1 = *(const bf16x8*)(Pw + ((c * 128 + 64 + g * 16) ^ ((c & 7) << 4)));
      Ov[0][qf] = __builtin_amdgcn_mfma_f32_16x16x32_bf16(vfr[0][0], pb0, Ov[0][qf], 0, 0, 0);
      Ov[1][qf] = __builtin_amdgcn_mfma_f32_16x16x32_bf16(vfr[0][1], pb0, Ov[1][qf], 0, 0, 0);
      Ov[0][qf] = __builtin_amdgcn_mfma_f32_16x16x32_bf16(vfr[1][0], pb1, Ov[0][qf], 0, 0, 0);
      Ov[1][qf] = __builtin_amdgcn_mfma_f32_16x16x32_bf16(vfr[1][1], pb1, Ov[1][qf], 0, 0, 0);
    }

#pragma unroll
    for (int qf = 0; qf < 4; ++qf)
#pragma unroll
      for (int dt = 0; dt < 2; ++dt) {
        int row = (b * 256 + n) * 64 + qf * 16 + c;
        bf16x4 ov;
        ov[0] = (bf16_t)Ov[dt][qf][0]; ov[1] = (bf16_t)Ov[dt][qf][1];
        ov[2] = (bf16_t)Ov[dt][qf][2]; ov[3] = (bf16_t)Ov[dt][qf][3];
        *(bf16x4*)(O + (size_t)row * 256 + 32 * h + dt * 16 + 4 * g) = ov;
      }
  } else {
    // ---------- branch 2: block=(b,m,h), wave=qtile, flash over 4 key tiles ----------
    const int h = idx & 3, m = (idx >> 2) & 63, b = idx >> 8;
    const int wid = tid >> 6;
    char* Pw = lds + 37376 + wid * 2048;
    const char* kvbase = (const char*)QKV + (size_t)(b * 16384 + m) * 1536;

#pragma unroll
    for (int it = 0; it < 4; ++it) {
      int i2 = it * 256 + tid;
      int key = i2 >> 2, ch4 = i2 & 3;
      int4 kk = *(const int4*)(kvbase + (size_t)key * 98304 + 768 + 64 * h + ch4 * 16);
      *(int4*)(lds + key * 80 + ch4 * 16) = kk;
    }
#pragma unroll
    for (int it = 0; it < 4; ++it) {
      int i2 = it * 256 + tid;
      int nn = i2 >> 2, dq = i2 & 3;
      bf16x8 vv = *(const bf16x8*)(kvbase + (size_t)nn * 98304 + 1280 + 64 * h + dq * 16);
#pragma unroll
      for (int j = 0; j < 8; ++j)
        *(bf16_t*)(lds + 20480 + swz((dq * 8 + j) * 528 + nn * 2)) = vv[j];
    }

    bf16x8 qa[4];
#pragma unroll
    for (int qf = 0; qf < 4; ++qf)
      qa[qf] = *(const bf16x8*)((const char*)QKV +
          (size_t)((b * 256 + wid * 64 + qf * 16 + c) * 64 + m) * 1536 + 256 + 64 * h + 16 * g);
    __syncthreads();

    f32x4 Ov[2][4];
    float lrun[4];
#pragma unroll
    for (int qf = 0; qf < 4; ++qf) {
      Ov[0][qf] = 0.f; Ov[1][qf] = 0.f;
      lrun[qf] = 0.f;
    }

    for (int kt = 0; kt < 4; ++kt) {
      bf16x8 kfr[4];
#pragma unroll
      for (int kf = 0; kf < 4; ++kf)
        kfr[kf] = *(const bf16x8*)(lds + (kt * 64 + kf * 16 + c) * 80 + 16 * g);
      bf16x8 vfr[2][2];
#pragma unroll
      for (int kb = 0; kb < 2; ++kb)
#pragma unroll
        for (int dt = 0; dt < 2; ++dt)
          vfr[kb][dt] = *(const bf16x8*)(lds + 20480 +
              swz((dt * 16 + c) * 528 + kt * 128 + kb * 64 + g * 16));

#pragma unroll
      for (int qf = 0; qf < 4; ++qf) {
        const float* pp = pos2 + ((h * 256 + wid * 64 + qf * 16 + c) * 256 + kt * 64 + 4 * g);
        f32x4 pv[4];
#pragma unroll
        for (int kf = 0; kf < 4; ++kf) pv[kf] = *(const f32x4*)(pp + kf * 16);
        f32x4 S[4];
#pragma unroll
        for (int kf = 0; kf < 4; ++kf) {
          S[kf] = 0.f;
          S[kf] = __builtin_amdgcn_mfma_f32_16x16x32_bf16(kfr[kf], qa[qf], S[kf], 0, 0, 0);
        }
#pragma unroll
        for (int kf = 0; kf < 4; ++kf) S[kf] = S[kf] * SCALE_F + pv[kf];
        // fixed-max: no running max, no rescale; l just accumulates
        float ls = 0.f;
#pragma unroll
        for (int kf = 0; kf < 4; ++kf)
#pragma unroll
          for (int r = 0; r < 4; ++r) {
            S[kf][r] = __expf(S[kf][r] - FIXMAX);
            ls += S[kf][r];
          }
        ls += __shfl_xor(ls, 16);
        ls += __shfl_xor(ls, 32);
        lrun[qf] += ls;
#pragma unroll
        for (int kf = 0; kf < 4; ++kf)
#pragma unroll
          for (int p = 0; p < 2; ++p) {
            bf16x2 w;
            w[0] = (bf16_t)S[kf][2 * p];
            w[1] = (bf16_t)S[kf][2 * p + 1];
            int byteo = c * 128 + kf * 32 + g * 8 + p * 4;
            *(bf16x2*)(Pw + (byteo ^ ((c & 7) << 4))) = w;
          }
        bf16x8 pb0 = *(const bf16x8*)(Pw + ((c * 128 + g * 16) ^ ((c & 7) << 4)));
        bf16x8 pb1 = *(const bf16x8*)(Pw + ((c * 128 + 64 + g * 16) ^ ((c & 7) << 4)));
        Ov[0][qf] = __builtin_amdgcn_mfma_f32_16x16x32_bf16(vfr[0][0], pb0, Ov[0][qf], 0, 0, 0);
        Ov[1][qf] = __builtin_amdgcn_mfma_f32_16x16x32_bf16(vfr[0][1], pb0, Ov[1][qf], 0, 0, 0);
        Ov[0][qf] = __builtin_amdgcn_mfma_f32_16x16x32_bf16(vfr[1][0], pb1, Ov[0][qf], 0, 0, 0);
        Ov[1][qf] = __builtin_amdgcn_mfma_f32_16x16x32_bf16(vfr[1][1], pb1, Ov[1][qf], 0, 0, 0);
      }
    }

#pragma unroll
    for (int qf = 0; qf < 4; ++qf) {
      float inv = 1.0f / lrun[qf];
      int qrow = (b * 256 + wid * 64 + qf * 16 + c) * 64 + m;
#pragma unroll
      for (int dt = 0; dt < 2; ++dt) {
        bf16x4 ov;
        ov[0] = (bf16_t)(Ov[dt][qf][0] * inv); ov[1] = (bf16_t)(Ov[dt][qf][1] * inv);
        ov[2] = (bf16_t)(Ov[dt][qf][2] * inv); ov[3] = (bf16_t)(Ov[dt][qf][3] * inv);
        *(bf16x4*)(O + (size_t)qrow * 256 + 128 + 32 * h + dt * 16 + 4 * g) = ov;
      }
    }
  }
}

// ---------------- GEMM3: out = attnO @ Wo + bo, unwindowed ----------------
__global__ __launch_bounds__(256) void gemm_out_k(
    const bf16_t* __restrict__ A, const bf16_t* __restrict__ Wt,
    const float* __restrict__ bo, float* __restrict__ out) {
  __shared__ bf16_t As[128 * 32];
  __shared__ bf16_t Bs[128 * 32];
  const int tid = threadIdx.x;
  const int row0 = blockIdx.x * 128;
  const int col0 = blockIdx.y * 128;
  const int lane = tid & 63, wv = tid >> 6;
  const int wm = (wv >> 1) * 64, wn = (wv & 1) * 64;
  const int tr = tid >> 2, kb = (tid & 3) * 8;

  const bf16_t* asrc0 = A + (size_t)(row0 + tr) * 256 + kb;
  const bf16_t* asrc1 = A + (size_t)(row0 + tr + 64) * 256 + kb;
  const bf16_t* bsrc0 = Wt + (col0 + tr) * 256 + kb;
  const bf16_t* bsrc1 = Wt + (col0 + tr + 64) * 256 + kb;

  f32x4 acc[4][4];
#pragma unroll
  for (int m = 0; m < 4; ++m)
#pragma unroll
    for (int n = 0; n < 4; ++n) acc[m][n] = 0.f;

  for (int ks = 0; ks < 256; ks += 32) {
    __syncthreads();
    *(int4*)&As[tr * 32 + kb] = *(const int4*)(asrc0 + ks);
    *(int4*)&As[(tr + 64) * 32 + kb] = *(const int4*)(asrc1 + ks);
    *(int4*)&Bs[tr * 32 + kb] = *(const int4*)(bsrc0 + ks);
    *(int4*)&Bs[(tr + 64) * 32 + kb] = *(const int4*)(bsrc1 + ks);
    __syncthreads();
    bf16x8 aF[4], bF[4];
#pragma unroll
    for (int m = 0; m < 4; ++m)
      aF[m] = *(const bf16x8*)&As[(wm + m * 16 + (lane & 15)) * 32 + (lane >> 4) * 8];
#pragma unroll
    for (int n = 0; n < 4; ++n)
      bF[n] = *(const bf16x8*)&Bs[(wn + n * 16 + (lane & 15)) * 32 + (lane >> 4) * 8];
#pragma unroll
    for (int m = 0; m < 4; ++m)
#pragma unroll
      for (int n = 0; n < 4; ++n)
        acc[m][n] = __builtin_amdgcn_mfma_f32_16x16x32_bf16(aF[m], bF[n], acc[m][n], 0, 0, 0);
  }

  float bias[4];
#pragma unroll
  for (int n = 0; n < 4; ++n) bias[n] = bo[col0 + wn + n * 16 + (lane & 15)];

#pragma unroll
  for (int m = 0; m < 4; ++m) {
#pragma unroll
    for (int r = 0; r < 4; ++r) {
      int grow = row0 + wm + m * 16 + ((lane >> 4) << 2) + r;
      int tok = token_of_row(grow);
      float* dst = out + (size_t)tok * 256 + col0 + wn + (lane & 15);
#pragma unroll
      for (int n = 0; n < 4; ++n) dst[n * 16] = acc[m][n][r] + bias[n];
    }
  }
}

extern "C" void kernel_launch(void* const* d_in, const int* in_sizes, int n_in,
                              void* d_out, int out_size, void* d_ws, size_t ws_size,
                              hipStream_t stream) {
  (void)in_sizes; (void)n_in; (void)out_size; (void)ws_size;
  const float* x    = (const float*)d_in[0];
  const float* Wq   = (const float*)d_in[1];
  const float* Wkv  = (const float*)d_in[2];
  const float* Wo   = (const float*)d_in[3];
  const float* bo   = (const float*)d_in[4];
  const float* pos1 = (const float*)d_in[5];
  const float* pos2 = (const float*)d_in[6];
  float* out = (float*)d_out;

  char* ws = (char*)d_ws;
  bf16_t* WqkvT = (bf16_t*)(ws);
  bf16_t* WoT   = (bf16_t*)(ws + 393216);
  bf16_t* QKVb  = (bf16_t*)(ws + 524288);
  bf16_t* attnO = (bf16_t*)(ws + 101187584ull);

  prep_k<<<1024, 256, 0, stream>>>(Wq, Wkv, Wo, WqkvT, WoT);
  gemm_qkv_k<<<512, 256, 0, stream>>>(x, WqkvT, QKVb);
  attn_k<<<2048, 256, 0, stream>>>(QKVb, pos1, pos2, attnO);
  dim3 g3(512, 2);
  gemm_out_k<<<g3, 256, 0, stream>>>(attnO, WoT, bo, out);
}